// Round 11
// baseline (345.263 us; speedup 1.0000x reference)
//
#include <hip/hip_runtime.h>
#include <hip/hip_bf16.h>
#include <math.h>

#define NN 50000
#define DD 128
#define BN_EPS 1e-5f
#define PADN 53248       // 1024 threads * 52 elems, >= NN, int4-aligned
#define GEMM_BLOCKS2 391 // (NN+127)/128
#define NBUCKET 32       // BN atomic buckets

typedef short short8 __attribute__((ext_vector_type(8)));
typedef float f32x4 __attribute__((ext_vector_type(4)));

__device__ __forceinline__ unsigned short f2bf(float f) {
    __hip_bfloat16 h = __float2bfloat16(f);
    return *reinterpret_cast<unsigned short*>(&h);
}
__device__ __forceinline__ float frcp(float x) { return __builtin_amdgcn_rcpf(x); }

// ---------------------------------------------------------------------------
// Prep + zero: blocks 0-3 build Wt[which][col][k] (bf16, transposed W);
// blocks 4-59 zero deg (PADN ints); block 4 also zeros acc2 (32x256 floats).
// ---------------------------------------------------------------------------
__global__ __launch_bounds__(256) void prep_w(
    const float* __restrict__ W0, const float* __restrict__ W1,
    const float* __restrict__ W2, const float* __restrict__ W3,
    unsigned short* __restrict__ Wt, int* __restrict__ deg,
    float* __restrict__ acc2)
{
    const int b = blockIdx.x;
    if (b >= 4) {
        const int zb = b - 4;                       // 0..55
        const int idx = zb * 256 + threadIdx.x;     // 0..14335
        if (idx < PADN / 4) ((int4*)deg)[idx] = make_int4(0, 0, 0, 0);
        if (zb == 0) {
            #pragma unroll
            for (int j = 0; j < 8; ++j)             // 2048 float4 = 32KB
                ((float4*)acc2)[j * 256 + threadIdx.x] =
                    make_float4(0.f, 0.f, 0.f, 0.f);
        }
        return;
    }
    const int which = b;
    const float* W = (which == 0) ? W0 : (which == 1) ? W1 : (which == 2) ? W2 : W3;
    unsigned short* O = Wt + (size_t)which * 16384;
    for (int it = 0; it < 8; ++it) {
        const int id = it * 256 + threadIdx.x;   // 0..2047
        const int col = id >> 4;                 // 0..127
        const int kc  = id & 15;                 // 0..15 (8 k each)
        unsigned int pk[4];
        #pragma unroll
        for (int p = 0; p < 4; ++p) {
            const float f0 = W[(kc * 8 + p * 2 + 0) * DD + col];
            const float f1 = W[(kc * 8 + p * 2 + 1) * DD + col];
            pk[p] = (unsigned int)f2bf(f0) | ((unsigned int)f2bf(f1) << 16);
        }
        uint4 v = make_uint4(pk[0], pk[1], pk[2], pk[3]);
        *(uint4*)(O + col * 128 + kc * 8) = v;
    }
}

// ---------------------------------------------------------------------------
// One 64-row MFMA tile: compute 4 projections and store.
// ---------------------------------------------------------------------------
__device__ __forceinline__ void gemm_tile(
    const char* xs, const char* wb, int p, int h, int lr, int lg,
    int rowbase, const float* __restrict__ bias,
    float* __restrict__ AX, float* __restrict__ QX,
    unsigned short* __restrict__ BD)
{
    f32x4 acc[4][4];
    #pragma unroll
    for (int m = 0; m < 4; ++m)
        #pragma unroll
        for (int n = 0; n < 4; ++n)
            acc[m][n] = (f32x4){0.f, 0.f, 0.f, 0.f};

    #pragma unroll
    for (int k = 0; k < 4; ++k) {
        short8 aW[4];
        #pragma unroll
        for (int n = 0; n < 4; ++n)
            aW[n] = *(const short8*)(wb + (n * 16 + lr) * 256 + k * 64 + lg * 16);
        short8 bX[4];
        #pragma unroll
        for (int m = 0; m < 4; ++m)
            bX[m] = *(const short8*)(xs + (m * 16 + lr) * 256 +
                                     ((k * 64 + lg * 16) ^ ((lr & 7) << 4)));
        #pragma unroll
        for (int m = 0; m < 4; ++m)
            #pragma unroll
            for (int n = 0; n < 4; ++n)
                acc[m][n] = __builtin_amdgcn_mfma_f32_16x16x32_bf16(
                    aW[n], bX[m], acc[m][n], 0, 0, 0);
    }

    #pragma unroll
    for (int n = 0; n < 4; ++n) {
        const int cbase = h * 64 + n * 16 + lg * 4;
        const float4 bv = *(const float4*)(bias + cbase);
        #pragma unroll
        for (int m = 0; m < 4; ++m) {
            const int row = rowbase + m * 16 + lr;
            if (row < NN) {
                float v0 = acc[m][n][0] + bv.x;
                float v1 = acc[m][n][1] + bv.y;
                float v2 = acc[m][n][2] + bv.z;
                float v3 = acc[m][n][3] + bv.w;
                if (p == 0) {
                    *(float4*)(AX + (size_t)row * DD + cbase) = make_float4(v0, v1, v2, v3);
                } else if (p == 3) {
                    *(float4*)(QX + (size_t)row * DD + cbase) =
                        make_float4(__expf(-v0), __expf(-v1), __expf(-v2), __expf(-v3));
                } else {
                    if (p == 2) {
                        v0 = __expf(-v0); v1 = __expf(-v1);
                        v2 = __expf(-v2); v3 = __expf(-v3);
                    }
                    uint2 pk;
                    pk.x = (unsigned int)f2bf(v0) | ((unsigned int)f2bf(v1) << 16);
                    pk.y = (unsigned int)f2bf(v2) | ((unsigned int)f2bf(v3) << 16);
                    char* dstp = (char*)BD + (size_t)row * 512 + (cbase >> 2) * 16
                               + ((p == 2) ? 8 : 0);
                    *(uint2*)dstp = pk;
                }
            }
        }
    }
}

// ---------------------------------------------------------------------------
// Merged: blocks [0, scb)   = scatter (counting-sort fill, 1 edge/thread,
//                             dispatched FIRST so it overlaps the GEMM);
//         blocks [scb, ...) = software-pipelined 128-row 4-projection GEMM.
// Pipeline: stage t0 -> issue t1 loads -> compute t0 -> cvt+store t1 ->
// compute t1 (t1 HBM latency hides under t0 MFMA+epilogue).
// ---------------------------------------------------------------------------
__global__ __launch_bounds__(512, 4) void gemm4_scatter(
    const float* __restrict__ X, const unsigned short* __restrict__ Wt,
    const float* __restrict__ bA, const float* __restrict__ bB,
    const float* __restrict__ bD, const float* __restrict__ bE,
    float* __restrict__ AX, float* __restrict__ QX,
    unsigned short* __restrict__ BD,
    const int* __restrict__ src, const int* __restrict__ dst,
    int* __restrict__ cursor, int* __restrict__ srt, int ne)
{
    const int scb = (ne + 511) >> 9;
    if (blockIdx.x < scb) {
        const int e = blockIdx.x * 512 + threadIdx.x;
        if (e < ne) {
            const int p = atomicAdd(&cursor[dst[e]], 1);
            srt[p] = src[e];
        }
        return;
    }

    __shared__ char xs[64 * 256];   // 64 rows x 128 bf16, XOR-swizzled
    const int gb   = blockIdx.x - scb;
    const int row0 = gb * 128;
    const int tid  = threadIdx.x;
    const int r0 = tid >> 4;        // rows r0 and r0+32 per thread
    const int c0 = tid & 15;        // 16B chunk in row

#define LDROW(row, va, vb)                                                   \
    {                                                                        \
        if ((row) < NN) {                                                    \
            const float* gp = X + (size_t)(row) * DD + c0 * 8;               \
            va = *(const float4*)(gp);                                       \
            vb = *(const float4*)(gp + 4);                                   \
        } else {                                                             \
            va = make_float4(0.f, 0.f, 0.f, 0.f);                           \
            vb = make_float4(0.f, 0.f, 0.f, 0.f);                           \
        }                                                                    \
    }
#define CVTSTORE(r, va, vb)                                                  \
    {                                                                        \
        uint4 pk;                                                            \
        pk.x = (unsigned int)f2bf(va.x) | ((unsigned int)f2bf(va.y) << 16);  \
        pk.y = (unsigned int)f2bf(va.z) | ((unsigned int)f2bf(va.w) << 16);  \
        pk.z = (unsigned int)f2bf(vb.x) | ((unsigned int)f2bf(vb.y) << 16);  \
        pk.w = (unsigned int)f2bf(vb.z) | ((unsigned int)f2bf(vb.w) << 16);  \
        *(uint4*)(xs + (r) * 256 + ((c0 * 16) ^ (((r) & 7) << 4))) = pk;     \
    }

    float4 va0, vb0, va1, vb1;
    // stage tile 0
    LDROW(row0 + r0, va0, vb0);
    LDROW(row0 + r0 + 32, va1, vb1);
    CVTSTORE(r0, va0, vb0);
    CVTSTORE(r0 + 32, va1, vb1);
    __syncthreads();

    const int wid  = tid >> 6;
    const int p    = wid >> 1;          // projection
    const int h    = wid & 1;           // column half
    const int lane = tid & 63;
    const int lr = lane & 15, lg = lane >> 4;
    const char* wb = (const char*)(Wt + (size_t)p * 16384) + h * 64 * 256;
    const float* bias = (p == 0) ? bA : (p == 1) ? bB : (p == 2) ? bD : bE;

    // issue tile-1 loads (latency hides under tile-0 compute)
    LDROW(row0 + 64 + r0, va0, vb0);
    LDROW(row0 + 64 + r0 + 32, va1, vb1);

    gemm_tile(xs, wb, p, h, lr, lg, row0, bias, AX, QX, BD);
    __syncthreads();

    CVTSTORE(r0, va0, vb0);
    CVTSTORE(r0 + 32, va1, vb1);
    __syncthreads();

    gemm_tile(xs, wb, p, h, lr, lg, row0 + 64, bias, AX, QX, BD);
#undef LDROW
#undef CVTSTORE
}

// ---------------------------------------------------------------------------
// Histogram of dst (1 edge/thread)
// ---------------------------------------------------------------------------
__global__ void hist_k(const int* __restrict__ dst, int* __restrict__ deg, int ne)
{
    const int e = blockIdx.x * blockDim.x + threadIdx.x;
    if (e < ne) atomicAdd(&deg[dst[e]], 1);
}

// ---------------------------------------------------------------------------
// One-kernel exclusive scan over PADN ints (deg zero-padded).
// ---------------------------------------------------------------------------
__global__ __launch_bounds__(1024) void scan_k(const int* __restrict__ deg,
                                               int* __restrict__ off,
                                               int* __restrict__ cursor)
{
    __shared__ int ws[16];
    const int t = threadIdx.x;
    int4 v[13];
    const int4* dp = (const int4*)deg + t * 13;
    #pragma unroll
    for (int j = 0; j < 13; ++j) v[j] = dp[j];

    int s = 0;
    #pragma unroll
    for (int j = 0; j < 13; ++j) s += v[j].x + v[j].y + v[j].z + v[j].w;

    int incl = s;
    #pragma unroll
    for (int o = 1; o < 64; o <<= 1) {
        const int u = __shfl_up(incl, o, 64);
        if ((t & 63) >= o) incl += u;
    }
    if ((t & 63) == 63) ws[t >> 6] = incl;
    __syncthreads();
    int wbase = 0;
    for (int i = 0; i < (t >> 6); ++i) wbase += ws[i];

    int run = wbase + incl - s;
    int4* op = (int4*)off + t * 13;
    int4* cp = (int4*)cursor + t * 13;
    #pragma unroll
    for (int j = 0; j < 13; ++j) {
        int4 w;
        w.x = run; run += v[j].x;
        w.y = run; run += v[j].y;
        w.z = run; run += v[j].z;
        w.w = run; run += v[j].w;
        op[j] = w;
        cp[j] = w;
    }
}

// ---------------------------------------------------------------------------
// Gate + weighted aggregation + snorm + BN partials (bucketed atomics).
// One WAVE per node (12500 blocks, dynamic balancing). sigma = 1/(1+P*Q).
// ---------------------------------------------------------------------------
__global__ __launch_bounds__(256) void agg_bn_k(
    const float* __restrict__ AX, const float* __restrict__ QX,
    const uint4* __restrict__ BD4, const float* __restrict__ X,
    const int* __restrict__ off, const int* __restrict__ srt,
    float* __restrict__ H, float* __restrict__ acc2)
{
    const int wid  = threadIdx.x >> 6;
    const int lane = threadIdx.x & 63;
    const int half = lane >> 5;
    const int f    = lane & 31;          // feature group: features 4f..4f+3
    const int node = blockIdx.x * 4 + wid;
    const int beg = off[node], end = off[node + 1];

    const float4 q = *(const float4*)(QX + (size_t)node * DD + f * 4);
    float num[4] = {0.f, 0.f, 0.f, 0.f};
    float den[4] = {0.f, 0.f, 0.f, 0.f};

#define EDGE4(wv)                                                            \
    {                                                                        \
        const float b0_ = __uint_as_float((wv).x << 16);                     \
        const float b1_ = __uint_as_float((wv).x & 0xffff0000u);             \
        const float b2_ = __uint_as_float((wv).y << 16);                     \
        const float b3_ = __uint_as_float((wv).y & 0xffff0000u);             \
        const float p0_ = __uint_as_float((wv).z << 16);                     \
        const float p1_ = __uint_as_float((wv).z & 0xffff0000u);             \
        const float p2_ = __uint_as_float((wv).w << 16);                     \
        const float p3_ = __uint_as_float((wv).w & 0xffff0000u);             \
        const float g0_ = frcp(fmaf(p0_, q.x, 1.0f));                        \
        const float g1_ = frcp(fmaf(p1_, q.y, 1.0f));                        \
        const float g2_ = frcp(fmaf(p2_, q.z, 1.0f));                        \
        const float g3_ = frcp(fmaf(p3_, q.w, 1.0f));                        \
        num[0] = fmaf(g0_, b0_, num[0]); den[0] += g0_;                      \
        num[1] = fmaf(g1_, b1_, num[1]); den[1] += g1_;                      \
        num[2] = fmaf(g2_, b2_, num[2]); den[2] += g2_;                      \
        num[3] = fmaf(g3_, b3_, num[3]); den[3] += g3_;                      \
    }

    int i = beg;
    for (; i + 8 <= end; i += 8) {       // 4 pairs = 8 edges in flight
        int ss[4];
        #pragma unroll
        for (int u = 0; u < 4; ++u) ss[u] = srt[i + 2 * u + half];
        uint4 wv[4];
        #pragma unroll
        for (int u = 0; u < 4; ++u) wv[u] = BD4[(size_t)ss[u] * 32 + f];
        #pragma unroll
        for (int u = 0; u < 4; ++u) EDGE4(wv[u]);
    }
    for (; i + 2 <= end; i += 2) {
        const int s = srt[i + half];
        const uint4 wv = BD4[(size_t)s * 32 + f];
        EDGE4(wv);
    }
    if (i < end && half == 0) {
        const int s = srt[i];
        const uint4 wv = BD4[(size_t)s * 32 + f];
        EDGE4(wv);
    }
#undef EDGE4

    #pragma unroll
    for (int j = 0; j < 4; ++j) {
        num[j] += __shfl_xor(num[j], 32);
        den[j] += __shfl_xor(den[j], 32);
    }

    float4 hv = make_float4(0.f, 0.f, 0.f, 0.f);
    if (half == 0) {
        if (end > beg) {
            const float4 ax = *(const float4*)(AX + (size_t)node * DD + f * 4);
            hv.x = ax.x + num[0] * frcp(den[0]);
            hv.y = ax.y + num[1] * frcp(den[1]);
            hv.z = ax.z + num[2] * frcp(den[2]);
            hv.w = ax.w + num[3] * frcp(den[3]);
        } else {
            hv = *(const float4*)(X + (size_t)node * DD + f * 4);
        }
        hv.x *= (1.0f / NN); hv.y *= (1.0f / NN);
        hv.z *= (1.0f / NN); hv.w *= (1.0f / NN);
        *(float4*)(H + (size_t)node * DD + f * 4) = hv;
    }

    // block BN reduce: [wave][f][c] -> 256 bucketed atomics
    __shared__ float red1[4][32][4], red2[4][32][4];
    if (half == 0) {
        red1[wid][f][0] = hv.x; red2[wid][f][0] = hv.x * hv.x;
        red1[wid][f][1] = hv.y; red2[wid][f][1] = hv.y * hv.y;
        red1[wid][f][2] = hv.z; red2[wid][f][2] = hv.z * hv.z;
        red1[wid][f][3] = hv.w; red2[wid][f][3] = hv.w * hv.w;
    }
    __syncthreads();
    const int t = threadIdx.x;
    if (t < 128) {
        const int ff = t >> 2, cc = t & 3;
        const float a1 = red1[0][ff][cc] + red1[1][ff][cc]
                       + red1[2][ff][cc] + red1[3][ff][cc];
        const float a2 = red2[0][ff][cc] + red2[1][ff][cc]
                       + red2[2][ff][cc] + red2[3][ff][cc];
        float* bucket = acc2 + (size_t)(blockIdx.x & (NBUCKET - 1)) * 256;
        atomicAdd(&bucket[t], a1);
        atomicAdd(&bucket[128 + t], a2);
    }
}

// ---------------------------------------------------------------------------
// Final: reduce 32 BN buckets once per block (LDS), then
// out = X + relu(BN(H)), float4/thread, 8 groups/thread grid-stride.
// ---------------------------------------------------------------------------
__global__ __launch_bounds__(256) void final_k(
    const float* __restrict__ H, const float* __restrict__ X,
    const float* __restrict__ acc2,
    const float* __restrict__ gamma, const float* __restrict__ beta,
    float* __restrict__ out)
{
    __shared__ float stat[256];
    const int t = threadIdx.x;
    {
        float s = 0.f;
        #pragma unroll
        for (int k = 0; k < NBUCKET; ++k) s += acc2[k * 256 + t];
        stat[t] = s;
    }
    __syncthreads();

    #pragma unroll
    for (int it = 0; it < 8; ++it) {
        const int i = (blockIdx.x * 8 + it) * 256 + t;   // float4-group index
        if (i >= NN * 32) return;
        const int f = (i & 31) * 4;
        const float4 h = *(const float4*)(H + (size_t)i * 4);
        const float4 x = *(const float4*)(X + (size_t)i * 4);
        float4 o;
        #pragma unroll
        for (int c = 0; c < 4; ++c) {
            const float mean = stat[f + c] * (1.0f / NN);
            const float var  = stat[128 + f + c] * (1.0f / NN) - mean * mean;
            const float rstd = rsqrtf(var + BN_EPS);
            const float hv = (c == 0) ? h.x : (c == 1) ? h.y : (c == 2) ? h.z : h.w;
            const float xv = (c == 0) ? x.x : (c == 1) ? x.y : (c == 2) ? x.z : x.w;
            float v = (hv - mean) * rstd * gamma[f + c] + beta[f + c];
            v = fmaxf(v, 0.f);
            const float r = xv + v;
            if (c == 0) o.x = r; else if (c == 1) o.y = r; else if (c == 2) o.z = r; else o.w = r;
        }
        *(float4*)(out + (size_t)i * 4) = o;
    }
}

// ---------------------------------------------------------------------------
extern "C" void kernel_launch(void* const* d_in, const int* in_sizes, int n_in,
                              void* d_out, int out_size, void* d_ws, size_t ws_size,
                              hipStream_t stream)
{
    const float* X     = (const float*)d_in[0];
    const float* W_A   = (const float*)d_in[1];
    const float* b_A   = (const float*)d_in[2];
    const float* W_B   = (const float*)d_in[3];
    const float* b_B   = (const float*)d_in[4];
    const float* W_D   = (const float*)d_in[5];
    const float* b_D   = (const float*)d_in[6];
    const float* W_E   = (const float*)d_in[7];
    const float* b_E   = (const float*)d_in[8];
    const float* gamma = (const float*)d_in[9];
    const float* beta  = (const float*)d_in[10];
    const int*   src   = (const int*)d_in[11];
    const int*   dst   = (const int*)d_in[12];
    const int    ne    = in_sizes[11];
    float* out = (float*)d_out;

    // workspace layout (16B-aligned chunks)
    char* w = (char*)d_ws;
    const size_t ndf = (size_t)NN * DD * sizeof(float);
    unsigned short* Wt = (unsigned short*)w;  w += 4 * 16384 * sizeof(unsigned short);
    float* AX = (float*)w;                    w += ndf;
    float* QX = (float*)w;                    w += ndf;
    unsigned short* BD = (unsigned short*)w;  w += (size_t)NN * 256 * sizeof(unsigned short);
    float* H  = (float*)w;                    w += ndf;
    float* acc2 = (float*)w;                  w += NBUCKET * 256 * sizeof(float);
    int* deg    = (int*)w;                    w += (size_t)PADN * sizeof(int);
    int* off    = (int*)w;                    w += (size_t)PADN * sizeof(int);
    int* cursor = (int*)w;                    w += (size_t)PADN * sizeof(int);
    int* srt    = (int*)w;                    w += (size_t)ne * sizeof(int);

    // 1) weight prep + zero deg/acc2
    prep_w<<<60, 256, 0, stream>>>(W_A, W_B, W_D, W_E, Wt, deg, acc2);

    // 2) counting sort: histogram + scan
    hist_k<<<(ne + 255) / 256, 256, 0, stream>>>(dst, deg, ne);
    scan_k<<<1, 1024, 0, stream>>>(deg, off, cursor);

    // 3) fused scatter (first) + pipelined 128-row GEMM
    const int sc_blocks = (ne + 511) / 512;
    gemm4_scatter<<<sc_blocks + GEMM_BLOCKS2, 512, 0, stream>>>(
        X, Wt, b_A, b_B, b_D, b_E, AX, QX, BD, src, dst, cursor, srt, ne);

    // 4) gate + aggregation + snorm + BN partials (one wave per node)
    agg_bn_k<<<NN / 4, 256, 0, stream>>>(AX, QX, (const uint4*)BD, X, off, srt, H, acc2);

    // 5) final (bucket reduce + BN + relu + residual)
    final_k<<<(NN * 32 + 2047) / 2048, 256, 0, stream>>>(H, X, acc2, gamma, beta, out);
}

// Round 12
// 268.075 us; speedup vs baseline: 1.2879x; 1.2879x over previous
//
#include <hip/hip_runtime.h>
#include <hip/hip_bf16.h>
#include <math.h>

#define NN 50000
#define DD 128
#define BN_EPS 1e-5f
#define PADN 53248      // 1024 threads * 52 elems, >= NN, int4-aligned
#define GEMM_BLOCKS 782 // (NN+63)/64
#define NBUCKET 32      // BN atomic buckets

typedef short short8 __attribute__((ext_vector_type(8)));
typedef float f32x4 __attribute__((ext_vector_type(4)));

__device__ __forceinline__ unsigned short f2bf(float f) {
    __hip_bfloat16 h = __float2bfloat16(f);
    return *reinterpret_cast<unsigned short*>(&h);
}
__device__ __forceinline__ float frcp(float x) { return __builtin_amdgcn_rcpf(x); }

// ---------------------------------------------------------------------------
// Prep + zero: blocks 0-3 build Wt[which][col][k] (bf16, transposed W);
// blocks 4-59 zero deg (PADN ints); block 4 also zeros acc2 (32x256 floats).
// ---------------------------------------------------------------------------
__global__ __launch_bounds__(256) void prep_w(
    const float* __restrict__ W0, const float* __restrict__ W1,
    const float* __restrict__ W2, const float* __restrict__ W3,
    unsigned short* __restrict__ Wt, int* __restrict__ deg,
    float* __restrict__ acc2)
{
    const int b = blockIdx.x;
    if (b >= 4) {
        const int zb = b - 4;                       // 0..55
        const int idx = zb * 256 + threadIdx.x;     // 0..14335
        if (idx < PADN / 4) ((int4*)deg)[idx] = make_int4(0, 0, 0, 0);
        if (zb == 0) {
            #pragma unroll
            for (int j = 0; j < 8; ++j)             // 2048 float4 = 32KB
                ((float4*)acc2)[j * 256 + threadIdx.x] =
                    make_float4(0.f, 0.f, 0.f, 0.f);
        }
        return;
    }
    const int which = b;
    const float* W = (which == 0) ? W0 : (which == 1) ? W1 : (which == 2) ? W2 : W3;
    unsigned short* O = Wt + (size_t)which * 16384;
    for (int it = 0; it < 8; ++it) {
        const int id = it * 256 + threadIdx.x;   // 0..2047
        const int col = id >> 4;                 // 0..127
        const int kc  = id & 15;                 // 0..15 (8 k each)
        unsigned int pk[4];
        #pragma unroll
        for (int p = 0; p < 4; ++p) {
            const float f0 = W[(kc * 8 + p * 2 + 0) * DD + col];
            const float f1 = W[(kc * 8 + p * 2 + 1) * DD + col];
            pk[p] = (unsigned int)f2bf(f0) | ((unsigned int)f2bf(f1) << 16);
        }
        uint4 v = make_uint4(pk[0], pk[1], pk[2], pk[3]);
        *(uint4*)(O + col * 128 + kc * 8) = v;
    }
}

// ---------------------------------------------------------------------------
// Histogram of dst; also records each edge's rank within its bucket
// (atomicAdd return value) so the scatter needs NO atomics.
// ---------------------------------------------------------------------------
__global__ void hist_k(const int* __restrict__ dst, int* __restrict__ deg,
                       int* __restrict__ rank, int ne)
{
    const int e = blockIdx.x * blockDim.x + threadIdx.x;
    if (e < ne) rank[e] = atomicAdd(&deg[dst[e]], 1);
}

// ---------------------------------------------------------------------------
// One-kernel exclusive scan over PADN ints (deg zero-padded) -> off.
// ---------------------------------------------------------------------------
__global__ __launch_bounds__(1024) void scan_k(const int* __restrict__ deg,
                                               int* __restrict__ off)
{
    __shared__ int ws[16];
    const int t = threadIdx.x;
    int4 v[13];
    const int4* dp = (const int4*)deg + t * 13;
    #pragma unroll
    for (int j = 0; j < 13; ++j) v[j] = dp[j];

    int s = 0;
    #pragma unroll
    for (int j = 0; j < 13; ++j) s += v[j].x + v[j].y + v[j].z + v[j].w;

    int incl = s;
    #pragma unroll
    for (int o = 1; o < 64; o <<= 1) {
        const int u = __shfl_up(incl, o, 64);
        if ((t & 63) >= o) incl += u;
    }
    if ((t & 63) == 63) ws[t >> 6] = incl;
    __syncthreads();
    int wbase = 0;
    for (int i = 0; i < (t >> 6); ++i) wbase += ws[i];

    int run = wbase + incl - s;
    int4* op = (int4*)off + t * 13;
    #pragma unroll
    for (int j = 0; j < 13; ++j) {
        int4 w;
        w.x = run; run += v[j].x;
        w.y = run; run += v[j].y;
        w.z = run; run += v[j].z;
        w.w = run; run += v[j].w;
        op[j] = w;
    }
}

// ---------------------------------------------------------------------------
// Merged: blocks [0, GEMM_BLOCKS) = fused 4-projection MFMA GEMM (FIRST —
// proven ordering: scatter backfills after the GEMM streaming phase);
// blocks [GEMM_BLOCKS, ...) = atomic-free scatter: srt[off[d]+rank[e]] = src.
// ---------------------------------------------------------------------------
__global__ __launch_bounds__(512, 4) void gemm4_scatter(
    const float* __restrict__ X, const unsigned short* __restrict__ Wt,
    const float* __restrict__ bA, const float* __restrict__ bB,
    const float* __restrict__ bD, const float* __restrict__ bE,
    float* __restrict__ AX, float* __restrict__ QX,
    unsigned short* __restrict__ BD,
    const int* __restrict__ src, const int* __restrict__ dst,
    const int* __restrict__ off, const int* __restrict__ rank,
    int* __restrict__ srt, int ne)
{
    if (blockIdx.x >= GEMM_BLOCKS) {
        const int e = (blockIdx.x - GEMM_BLOCKS) * 512 + threadIdx.x;
        if (e < ne) {
            srt[off[dst[e]] + rank[e]] = src[e];
        }
        return;
    }

    __shared__ char xs[64 * 256];   // 64 rows x 128 bf16, XOR-swizzled
    const int row0 = blockIdx.x * 64;
    const int tid  = threadIdx.x;

    #pragma unroll
    for (int it = 0; it < 2; ++it) {
        const int idx = it * 512 + tid;     // 0..1023
        const int r = idx >> 4;             // 0..63
        const int c = idx & 15;             // 16B chunk in row
        const bool valid = (row0 + r) < NN;
        float4 va = make_float4(0.f, 0.f, 0.f, 0.f);
        float4 vb = make_float4(0.f, 0.f, 0.f, 0.f);
        if (valid) {
            const float* gp = X + (size_t)(row0 + r) * DD + c * 8;
            va = *(const float4*)(gp);
            vb = *(const float4*)(gp + 4);
        }
        uint4 pk;
        pk.x = (unsigned int)f2bf(va.x) | ((unsigned int)f2bf(va.y) << 16);
        pk.y = (unsigned int)f2bf(va.z) | ((unsigned int)f2bf(va.w) << 16);
        pk.z = (unsigned int)f2bf(vb.x) | ((unsigned int)f2bf(vb.y) << 16);
        pk.w = (unsigned int)f2bf(vb.z) | ((unsigned int)f2bf(vb.w) << 16);
        *(uint4*)(xs + r * 256 + ((c * 16) ^ ((r & 7) << 4))) = pk;
    }
    __syncthreads();

    const int wid  = tid >> 6;
    const int p    = wid >> 1;          // projection
    const int h    = wid & 1;           // column half
    const int lane = tid & 63;
    const int lr = lane & 15, lg = lane >> 4;

    f32x4 acc[4][4];
    #pragma unroll
    for (int m = 0; m < 4; ++m)
        #pragma unroll
        for (int n = 0; n < 4; ++n)
            acc[m][n] = (f32x4){0.f, 0.f, 0.f, 0.f};

    const char* wb = (const char*)(Wt + (size_t)p * 16384) + h * 64 * 256;

    #pragma unroll
    for (int k = 0; k < 4; ++k) {
        short8 aW[4];
        #pragma unroll
        for (int n = 0; n < 4; ++n)
            aW[n] = *(const short8*)(wb + (n * 16 + lr) * 256 + k * 64 + lg * 16);
        short8 bX[4];
        #pragma unroll
        for (int m = 0; m < 4; ++m)
            bX[m] = *(const short8*)(xs + (m * 16 + lr) * 256 +
                                     ((k * 64 + lg * 16) ^ ((lr & 7) << 4)));
        #pragma unroll
        for (int m = 0; m < 4; ++m)
            #pragma unroll
            for (int n = 0; n < 4; ++n)
                acc[m][n] = __builtin_amdgcn_mfma_f32_16x16x32_bf16(
                    aW[n], bX[m], acc[m][n], 0, 0, 0);
    }

    const float* bias = (p == 0) ? bA : (p == 1) ? bB : (p == 2) ? bD : bE;
    #pragma unroll
    for (int n = 0; n < 4; ++n) {
        const int cbase = h * 64 + n * 16 + lg * 4;
        const float4 bv = *(const float4*)(bias + cbase);
        #pragma unroll
        for (int m = 0; m < 4; ++m) {
            const int row = row0 + m * 16 + lr;
            if (row < NN) {
                float v0 = acc[m][n][0] + bv.x;
                float v1 = acc[m][n][1] + bv.y;
                float v2 = acc[m][n][2] + bv.z;
                float v3 = acc[m][n][3] + bv.w;
                if (p == 0) {
                    *(float4*)(AX + (size_t)row * DD + cbase) = make_float4(v0, v1, v2, v3);
                } else if (p == 3) {
                    *(float4*)(QX + (size_t)row * DD + cbase) =
                        make_float4(__expf(-v0), __expf(-v1), __expf(-v2), __expf(-v3));
                } else {
                    if (p == 2) {
                        v0 = __expf(-v0); v1 = __expf(-v1);
                        v2 = __expf(-v2); v3 = __expf(-v3);
                    }
                    uint2 pk;
                    pk.x = (unsigned int)f2bf(v0) | ((unsigned int)f2bf(v1) << 16);
                    pk.y = (unsigned int)f2bf(v2) | ((unsigned int)f2bf(v3) << 16);
                    char* dstp = (char*)BD + (size_t)row * 512 + (cbase >> 2) * 16
                               + ((p == 2) ? 8 : 0);
                    *(uint2*)dstp = pk;
                }
            }
        }
    }
}

// ---------------------------------------------------------------------------
// Gate + weighted aggregation + snorm + BN partials (bucketed atomics).
// One WAVE per node (12500 blocks, dynamic balancing). sigma = 1/(1+P*Q).
// ---------------------------------------------------------------------------
__global__ __launch_bounds__(256) void agg_bn_k(
    const float* __restrict__ AX, const float* __restrict__ QX,
    const uint4* __restrict__ BD4, const float* __restrict__ X,
    const int* __restrict__ off, const int* __restrict__ srt,
    float* __restrict__ H, float* __restrict__ acc2)
{
    const int wid  = threadIdx.x >> 6;
    const int lane = threadIdx.x & 63;
    const int half = lane >> 5;
    const int f    = lane & 31;          // feature group: features 4f..4f+3
    const int node = blockIdx.x * 4 + wid;
    const int beg = off[node], end = off[node + 1];

    const float4 q = *(const float4*)(QX + (size_t)node * DD + f * 4);
    float num[4] = {0.f, 0.f, 0.f, 0.f};
    float den[4] = {0.f, 0.f, 0.f, 0.f};

#define EDGE4(wv)                                                            \
    {                                                                        \
        const float b0_ = __uint_as_float((wv).x << 16);                     \
        const float b1_ = __uint_as_float((wv).x & 0xffff0000u);             \
        const float b2_ = __uint_as_float((wv).y << 16);                     \
        const float b3_ = __uint_as_float((wv).y & 0xffff0000u);             \
        const float p0_ = __uint_as_float((wv).z << 16);                     \
        const float p1_ = __uint_as_float((wv).z & 0xffff0000u);             \
        const float p2_ = __uint_as_float((wv).w << 16);                     \
        const float p3_ = __uint_as_float((wv).w & 0xffff0000u);             \
        const float g0_ = frcp(fmaf(p0_, q.x, 1.0f));                        \
        const float g1_ = frcp(fmaf(p1_, q.y, 1.0f));                        \
        const float g2_ = frcp(fmaf(p2_, q.z, 1.0f));                        \
        const float g3_ = frcp(fmaf(p3_, q.w, 1.0f));                        \
        num[0] = fmaf(g0_, b0_, num[0]); den[0] += g0_;                      \
        num[1] = fmaf(g1_, b1_, num[1]); den[1] += g1_;                      \
        num[2] = fmaf(g2_, b2_, num[2]); den[2] += g2_;                      \
        num[3] = fmaf(g3_, b3_, num[3]); den[3] += g3_;                      \
    }

    int i = beg;
    for (; i + 8 <= end; i += 8) {       // 4 pairs = 8 edges in flight
        int ss[4];
        #pragma unroll
        for (int u = 0; u < 4; ++u) ss[u] = srt[i + 2 * u + half];
        uint4 wv[4];
        #pragma unroll
        for (int u = 0; u < 4; ++u) wv[u] = BD4[(size_t)ss[u] * 32 + f];
        #pragma unroll
        for (int u = 0; u < 4; ++u) EDGE4(wv[u]);
    }
    for (; i + 2 <= end; i += 2) {
        const int s = srt[i + half];
        const uint4 wv = BD4[(size_t)s * 32 + f];
        EDGE4(wv);
    }
    if (i < end && half == 0) {
        const int s = srt[i];
        const uint4 wv = BD4[(size_t)s * 32 + f];
        EDGE4(wv);
    }
#undef EDGE4

    #pragma unroll
    for (int j = 0; j < 4; ++j) {
        num[j] += __shfl_xor(num[j], 32);
        den[j] += __shfl_xor(den[j], 32);
    }

    float4 hv = make_float4(0.f, 0.f, 0.f, 0.f);
    if (half == 0) {
        if (end > beg) {
            const float4 ax = *(const float4*)(AX + (size_t)node * DD + f * 4);
            hv.x = ax.x + num[0] * frcp(den[0]);
            hv.y = ax.y + num[1] * frcp(den[1]);
            hv.z = ax.z + num[2] * frcp(den[2]);
            hv.w = ax.w + num[3] * frcp(den[3]);
        } else {
            hv = *(const float4*)(X + (size_t)node * DD + f * 4);
        }
        hv.x *= (1.0f / NN); hv.y *= (1.0f / NN);
        hv.z *= (1.0f / NN); hv.w *= (1.0f / NN);
        *(float4*)(H + (size_t)node * DD + f * 4) = hv;
    }

    // block BN reduce: [wave][f][c] -> 256 bucketed atomics
    __shared__ float red1[4][32][4], red2[4][32][4];
    if (half == 0) {
        red1[wid][f][0] = hv.x; red2[wid][f][0] = hv.x * hv.x;
        red1[wid][f][1] = hv.y; red2[wid][f][1] = hv.y * hv.y;
        red1[wid][f][2] = hv.z; red2[wid][f][2] = hv.z * hv.z;
        red1[wid][f][3] = hv.w; red2[wid][f][3] = hv.w * hv.w;
    }
    __syncthreads();
    const int t = threadIdx.x;
    if (t < 128) {
        const int ff = t >> 2, cc = t & 3;
        const float a1 = red1[0][ff][cc] + red1[1][ff][cc]
                       + red1[2][ff][cc] + red1[3][ff][cc];
        const float a2 = red2[0][ff][cc] + red2[1][ff][cc]
                       + red2[2][ff][cc] + red2[3][ff][cc];
        float* bucket = acc2 + (size_t)(blockIdx.x & (NBUCKET - 1)) * 256;
        atomicAdd(&bucket[t], a1);
        atomicAdd(&bucket[128 + t], a2);
    }
}

// ---------------------------------------------------------------------------
// Final: reduce 32 BN buckets once per block (LDS), then
// out = X + relu(BN(H)), float4/thread, 8 groups/thread grid-stride.
// ---------------------------------------------------------------------------
__global__ __launch_bounds__(256) void final_k(
    const float* __restrict__ H, const float* __restrict__ X,
    const float* __restrict__ acc2,
    const float* __restrict__ gamma, const float* __restrict__ beta,
    float* __restrict__ out)
{
    __shared__ float stat[256];
    const int t = threadIdx.x;
    {
        float s = 0.f;
        #pragma unroll
        for (int k = 0; k < NBUCKET; ++k) s += acc2[k * 256 + t];
        stat[t] = s;
    }
    __syncthreads();

    #pragma unroll
    for (int it = 0; it < 8; ++it) {
        const int i = (blockIdx.x * 8 + it) * 256 + t;   // float4-group index
        if (i >= NN * 32) return;
        const int f = (i & 31) * 4;
        const float4 h = *(const float4*)(H + (size_t)i * 4);
        const float4 x = *(const float4*)(X + (size_t)i * 4);
        float4 o;
        #pragma unroll
        for (int c = 0; c < 4; ++c) {
            const float mean = stat[f + c] * (1.0f / NN);
            const float var  = stat[128 + f + c] * (1.0f / NN) - mean * mean;
            const float rstd = rsqrtf(var + BN_EPS);
            const float hv = (c == 0) ? h.x : (c == 1) ? h.y : (c == 2) ? h.z : h.w;
            const float xv = (c == 0) ? x.x : (c == 1) ? x.y : (c == 2) ? x.z : x.w;
            float v = (hv - mean) * rstd * gamma[f + c] + beta[f + c];
            v = fmaxf(v, 0.f);
            const float r = xv + v;
            if (c == 0) o.x = r; else if (c == 1) o.y = r; else if (c == 2) o.z = r; else o.w = r;
        }
        *(float4*)(out + (size_t)i * 4) = o;
    }
}

// ---------------------------------------------------------------------------
extern "C" void kernel_launch(void* const* d_in, const int* in_sizes, int n_in,
                              void* d_out, int out_size, void* d_ws, size_t ws_size,
                              hipStream_t stream)
{
    const float* X     = (const float*)d_in[0];
    const float* W_A   = (const float*)d_in[1];
    const float* b_A   = (const float*)d_in[2];
    const float* W_B   = (const float*)d_in[3];
    const float* b_B   = (const float*)d_in[4];
    const float* W_D   = (const float*)d_in[5];
    const float* b_D   = (const float*)d_in[6];
    const float* W_E   = (const float*)d_in[7];
    const float* b_E   = (const float*)d_in[8];
    const float* gamma = (const float*)d_in[9];
    const float* beta  = (const float*)d_in[10];
    const int*   src   = (const int*)d_in[11];
    const int*   dst   = (const int*)d_in[12];
    const int    ne    = in_sizes[11];
    float* out = (float*)d_out;

    // workspace layout (16B-aligned chunks)
    char* w = (char*)d_ws;
    const size_t ndf = (size_t)NN * DD * sizeof(float);
    unsigned short* Wt = (unsigned short*)w;  w += 4 * 16384 * sizeof(unsigned short);
    float* AX = (float*)w;                    w += ndf;
    float* QX = (float*)w;                    w += ndf;
    unsigned short* BD = (unsigned short*)w;  w += (size_t)NN * 256 * sizeof(unsigned short);
    float* H  = (float*)w;                    w += ndf;
    float* acc2 = (float*)w;                  w += NBUCKET * 256 * sizeof(float);
    int* deg    = (int*)w;                    w += (size_t)PADN * sizeof(int);
    int* off    = (int*)w;                    w += (size_t)PADN * sizeof(int);
    int* rank   = (int*)w;                    w += (size_t)ne * sizeof(int);
    int* srt    = (int*)w;                    w += (size_t)ne * sizeof(int);

    // 1) weight prep + zero deg/acc2
    prep_w<<<60, 256, 0, stream>>>(W_A, W_B, W_D, W_E, Wt, deg, acc2);

    // 2) counting sort: histogram (+ per-edge rank) + scan
    hist_k<<<(ne + 255) / 256, 256, 0, stream>>>(dst, deg, rank, ne);
    scan_k<<<1, 1024, 0, stream>>>(deg, off);

    // 3) fused GEMM (first) + atomic-free scatter
    const int sc_blocks = (ne + 511) / 512;
    gemm4_scatter<<<GEMM_BLOCKS + sc_blocks, 512, 0, stream>>>(
        X, Wt, b_A, b_B, b_D, b_E, AX, QX, BD, src, dst, off, rank, srt, ne);

    // 4) gate + aggregation + snorm + BN partials (one wave per node)
    agg_bn_k<<<NN / 4, 256, 0, stream>>>(AX, QX, (const uint4*)BD, X, off, srt, H, acc2);

    // 5) final (bucket reduce + BN + relu + residual)
    final_k<<<(NN * 32 + 2047) / 2048, 256, 0, stream>>>(H, X, acc2, gamma, beta, out);
}